// Round 5
// baseline (19121.442 us; speedup 1.0000x reference)
//
#include <hip/hip_runtime.h>
#include <hip/hip_fp16.h>
#include <stdint.h>

// LSTM_29042568856007: B=64, T=4096, D=256, H=256.
// Round 9: MFMA rewrite. R4-R8 post-mortems: VALUBusy/instr-count reconciliation
// across rounds shows v_dot2_f32_f16 issues at ~4cyc/wave (half rate) -> the
// fdot2 family has a hard ~8ms floor and we sit at 2x it from serial-dep
// overhead; MfmaUtil was 0.0 in every round. This round moves the matmul to
// the (idle) matrix pipe and splits weights across CUs so residency is total:
//   grid = 16 WGs = 4 batch-groups (16 batches) x 4 slot-parts (256 gate-cols).
//   K=512 concat: gates = [h_t | x_t] @ [W_hh ; W_ih] (per-part slice).
//   Per-WG weights 256KB f16 = 64 B-frags = 256 VGPR/lane, ALL register
//   resident (256 thr, launch_bounds(256,1) -> 512-reg budget, asm-pinned
//   per R8's proven recipe). No weight streaming AT ALL.
//   h exchange per step: 2KB/WG -> LLC via relaxed agent atomics; flag
//   protocol: stores -> vmcnt(0) -> barrier -> flag=t+1 -> poll 4 flags ->
//   stage h into LDS A-frags. Double-buffered hglob + monotonic flags makes
//   overwrite-before-read impossible; spin is bounded (fail, not hang).
// ASSUMPTIONS (triage keys for next round):
//   A1: mfma_f32_16x16x32_f16 frag k-map = 4*(l>>4)+(j&3)+16*(j>>2) (+32*kk);
//       A: row=l&15, B: col=l&15; D: col=l&15, row=4*(l>>4)+reg (m89-verified).
//       If FAIL+fast: flip k-map to 8-contiguous (8*(l>>4)+j) in the 3 marked
//       spots (prep, x/h-stage, nothing else).
//   A2: relaxed AGENT atomics + vmcnt drain give cross-XCD visibility.
//   A3: 16 WGs co-resident (trivial vs 256 CUs).
//   A4: ws_size >= ~1.07 MB.

#define LSTM_B 64
#define LSTM_T 4096
#define LSTM_D 256
#define LSTM_H 256

#define WS_FLAGS_OFF (1u << 20)
#define WS_HG_OFF    ((1u << 20) + 4096u)
// ws total: 1MB frags + 1KB flags (64B stride) + 64KB hglob = ~1.07MB

typedef __attribute__((ext_vector_type(8))) _Float16 half8;
typedef __attribute__((ext_vector_type(4))) float f32x4;

static __device__ __forceinline__ float sigmoidf_(float x) {
    return 1.0f / (1.0f + __expf(-x));
}
static __device__ __forceinline__ float tanhf_(float x) {
    float ax = fabsf(x);
    float e  = __expf(-2.0f * ax);
    float t  = (1.0f - e) / (1.0f + e);
    return copysignf(t, x);
}

// ws frags: uint4 frag[T=64][kk=16][lane=64]; entry = 8 f16 (A1 layout).
// slot n = T*16 + (lane&15); source gate row r = (n&3)*256 + (n>>2)
// (gate-interleaved permutation so i/f/g/o of h-col j sit in one lane-quad).
// k = 32*kk + 4*(lane>>4) + (j&3) + 16*(j>>2); k<256 -> W_hh, else W_ih.
__global__ __launch_bounds__(256) void prep_frags(
    const float* __restrict__ W_ih, const float* __restrict__ W_hh,
    uint8_t* __restrict__ ws)
{
    int idx = blockIdx.x * blockDim.x + threadIdx.x;   // [0, 65536)
    uint4* Wp = (uint4*)ws;
    int lane = idx & 63;
    int kk   = (idx >> 6) & 15;
    int T    = idx >> 10;
    int n  = T * 16 + (lane & 15);
    int r  = ((n & 3) << 8) + (n >> 2);
    int kb = 32 * kk + 4 * (lane >> 4);                // A1 k-map (spot 1/3)
    uint32_t u[4];
    #pragma unroll
    for (int h = 0; h < 4; ++h) {
        uint32_t lohi[2];
        #pragma unroll
        for (int e = 0; e < 2; ++e) {
            int j = 2 * h + e;
            int k = kb + (j & 3) + 16 * (j >> 2);
            float v = (k < 256) ? W_hh[r * 256 + k] : W_ih[r * 256 + (k - 256)];
            lohi[e] = (uint32_t)__half_as_ushort(__float2half(v));
        }
        u[h] = lohi[0] | (lohi[1] << 16);
    }
    Wp[idx] = make_uint4(u[0], u[1], u[2], u[3]);
    if (idx < 16) ((uint32_t*)(ws + WS_FLAGS_OFF))[idx * 16] = 0u;  // re-zero each launch
}

__global__ __launch_bounds__(256, 1) void lstm_r9(
    const float* __restrict__ xs,      // [B, T, D] fp32
    const float* __restrict__ bias_g,  // [4H]
    uint8_t* __restrict__ ws,
    float* __restrict__ out)           // h[B,H] then c[B,H]
{
    const int tid = threadIdx.x;
    const int l   = tid & 63;
    const int w   = tid >> 6;            // wave [0,4)
    const int g   = blockIdx.x >> 2;     // batch-group: batches 16g..16g+15
    const int p   = blockIdx.x & 3;      // slot-part: slots 256p..256p+255

    const uint4* WF   = (const uint4*)ws;
    uint32_t* flags   = (uint32_t*)(ws + WS_FLAGS_OFF);
    uint32_t* hg32    = (uint32_t*)(ws + WS_HG_OFF);

    __shared__ uint4 hx[16 * 64];        // A-frags [kk][laneSlot], 16 KiB

    // ---- one-time: this WG's 64 B-frags into registers (256 VGPR) ----
    uint4 wf[4][16];
    #pragma unroll
    for (int tl = 0; tl < 4; ++tl) {
        int T = p * 16 + w * 4 + tl;
        #pragma unroll
        for (int kk = 0; kk < 16; ++kk)
            wf[tl][kk] = WF[(T * 16 + kk) * 64 + l];
    }
    #pragma unroll
    for (int tl = 0; tl < 4; ++tl)
        #pragma unroll
        for (int kk = 0; kk < 16; ++kk)
            asm volatile("" : "+v"(wf[tl][kk].x), "+v"(wf[tl][kk].y),
                              "+v"(wf[tl][kk].z), "+v"(wf[tl][kk].w));

    // ---- per-lane ew constants (D layout: col=l&15, row=4*(l>>4)+reg) ----
    const int  c2   = l & 3;             // gate index of own column
    const int  qa   = l >> 4;
    const bool c2b0 = (c2 & 1) != 0, c2b1 = (c2 & 2) != 0;
    const int  m_ew = 4 * qa + c2;       // batch row this lane finalizes
    float bias[4];
    int   jj[4];
    #pragma unroll
    for (int tl = 0; tl < 4; ++tl) {
        int T    = p * 16 + w * 4 + tl;
        int slot = T * 16 + (l & 15);
        int r    = ((slot & 3) << 8) + (slot >> 2);
        bias[tl] = bias_g[r];
        jj[tl]   = slot >> 2;            // global h-col [0,256)
    }

    // ---- x staging ids: thread covers (m_s, d0..d0+15) ----
    const int m_s = tid >> 4;
    const int d0  = (tid & 15) * 16;
    const float* xrow = xs + (size_t)(16 * g + m_s) * LSTM_T * LSTM_D + d0;

    // ---- prologue: zero h-region frags (kk 0..7), stage x(0), prefetch x(1) ----
    hx[tid]       = make_uint4(0, 0, 0, 0);
    hx[tid + 256] = make_uint4(0, 0, 0, 0);
    {
        float4 x0[4];
        #pragma unroll
        for (int i = 0; i < 4; ++i) x0[i] = ((const float4*)xrow)[i];
        #pragma unroll
        for (int i = 0; i < 4; ++i) {
            __half2 h0 = __floats2half2_rn(x0[i].x, x0[i].y);
            __half2 h1 = __floats2half2_rn(x0[i].z, x0[i].w);
            uint64_t v = (uint64_t)__builtin_bit_cast(uint32_t, h0)
                       | ((uint64_t)__builtin_bit_cast(uint32_t, h1) << 32);
            int k0 = 256 + d0 + 4 * i;                 // A1 k-map (spot 2/3)
            int kk = k0 >> 5, off = k0 & 31;
            int q = (off & 15) >> 2, hi = off >> 4;
            int slot = (m_s + 16 * q) ^ ((2 * kk) & 63);
            *(uint64_t*)((uint8_t*)hx + kk * 1024 + slot * 16 + hi * 8) = v;
        }
    }
    float4 xb[4];
    #pragma unroll
    for (int i = 0; i < 4; ++i) xb[i] = ((const float4*)(xrow + (size_t)1 * LSTM_D))[i];

    asm volatile("s_waitcnt lgkmcnt(0)\n\ts_barrier" ::: "memory");

    float cst[4] = {0, 0, 0, 0}, hst[4] = {0, 0, 0, 0};

    for (int t = 0; t < LSTM_T; ++t) {
        // ---- phase 1: read A-frags [h_t | x_t] into regs ----
        uint4 af[16];
        #pragma unroll
        for (int kk = 0; kk < 16; ++kk)
            af[kk] = hx[kk * 64 + (l ^ ((2 * kk) & 63))];
        asm volatile("s_waitcnt lgkmcnt(0)\n\ts_barrier" ::: "memory");  // B1

        // ---- phase 2: overwrite x-region with x(t+1); prefetch x(t+2) ----
        #pragma unroll
        for (int i = 0; i < 4; ++i) {
            __half2 h0 = __floats2half2_rn(xb[i].x, xb[i].y);
            __half2 h1 = __floats2half2_rn(xb[i].z, xb[i].w);
            uint64_t v = (uint64_t)__builtin_bit_cast(uint32_t, h0)
                       | ((uint64_t)__builtin_bit_cast(uint32_t, h1) << 32);
            int k0 = 256 + d0 + 4 * i;
            int kk = k0 >> 5, off = k0 & 31;
            int q = (off & 15) >> 2, hi = off >> 4;
            int slot = (m_s + 16 * q) ^ ((2 * kk) & 63);
            *(uint64_t*)((uint8_t*)hx + kk * 1024 + slot * 16 + hi * 8) = v;
        }
        {
            int tn = (t + 2 < LSTM_T) ? t + 2 : t;
            #pragma unroll
            for (int i = 0; i < 4; ++i)
                xb[i] = ((const float4*)(xrow + (size_t)tn * LSTM_D))[i];
        }

        // ---- phase 3: MFMA, 4 tiles x 16 kk ----
        f32x4 acc[4];
        #pragma unroll
        for (int tl = 0; tl < 4; ++tl)
            acc[tl] = (f32x4){bias[tl], bias[tl], bias[tl], bias[tl]};
        #pragma unroll
        for (int kk = 0; kk < 16; ++kk) {
            half8 a = __builtin_bit_cast(half8, af[kk]);
            #pragma unroll
            for (int tl = 0; tl < 4; ++tl)
                acc[tl] = __builtin_amdgcn_mfma_f32_16x16x32_f16(
                    a, __builtin_bit_cast(half8, wf[tl][kk]), acc[tl], 0, 0, 0);
        }

        // ---- phase 4: gate gather (quad cndmask+shfl), lstm ew, pack ----
        uint32_t hpair[4];
        #pragma unroll
        for (int tl = 0; tl < 4; ++tl) {
            f32x4 a = acc[tl];
            float s01  = c2b0 ? a.y : a.x;
            float s23  = c2b0 ? a.w : a.z;
            float s01b = c2b0 ? a.x : a.y;
            float s23b = c2b0 ? a.z : a.w;
            float own = c2b1 ? s23  : s01;   // own gate (c2), row m_ew
            float v1  = c2b1 ? s23b : s01b;  // reg c2^1
            float v2  = c2b1 ? s01  : s23;   // reg c2^2
            float v3  = c2b1 ? s01b : s23b;  // reg c2^3
            float r1 = __shfl_xor(v1, 1, 64);    // gate c2^1, row m_ew
            float r2 = __shfl_xor(v2, 2, 64);    // gate c2^2, row m_ew
            float r3 = __shfl_xor(v3, 3, 64);    // gate c2^3, row m_ew
            float gi = c2b1 ? (c2b0 ? r3 : r2) : (c2b0 ? r1 : own);
            float gf = c2b1 ? (c2b0 ? r2 : r3) : (c2b0 ? own : r1);
            float gg = c2b1 ? (c2b0 ? r1 : own) : (c2b0 ? r3 : r2);
            float go = c2b1 ? (c2b0 ? own : r1) : (c2b0 ? r2 : r3);
            float cc = cst[tl];
            cc = sigmoidf_(gf) * cc + sigmoidf_(gi) * tanhf_(gg);
            float hh = sigmoidf_(go) * tanhf_(cc);
            cst[tl] = cc; hst[tl] = hh;
            uint32_t u  = (uint32_t)__half_as_ushort(__float2half(hh));
            uint32_t up = (uint32_t)__shfl_xor((int)u, 4, 64);  // partner j^1
            hpair[tl] = (u & 0xffffu) | (up << 16);
        }

        // ---- phase 5: publish h-slice (agent atomics), flag, poll ----
        int buf = (t + 1) & 1;
        if ((l & 4) == 0) {   // even-j lanes hold the packed pair
            uint32_t* hgrow = hg32 + ((size_t)(g * 2 + buf) * 16 + m_ew) * 128;
            #pragma unroll
            for (int tl = 0; tl < 4; ++tl)
                __hip_atomic_store(&hgrow[jj[tl] >> 1], hpair[tl],
                                   __ATOMIC_RELAXED, __HIP_MEMORY_SCOPE_AGENT);
        }
        asm volatile("s_waitcnt vmcnt(0) lgkmcnt(0)\n\ts_barrier" ::: "memory"); // B2
        if (tid == 0)
            __hip_atomic_store(&flags[(g * 4 + p) * 16], (uint32_t)(t + 1),
                               __ATOMIC_RELAXED, __HIP_MEMORY_SCOPE_AGENT);
        {
            uint32_t tgt = (uint32_t)(t + 1);
            int spin = 0;
            while (true) {
                uint32_t f0 = __hip_atomic_load(&flags[(g * 4 + 0) * 16], __ATOMIC_RELAXED, __HIP_MEMORY_SCOPE_AGENT);
                uint32_t f1 = __hip_atomic_load(&flags[(g * 4 + 1) * 16], __ATOMIC_RELAXED, __HIP_MEMORY_SCOPE_AGENT);
                uint32_t f2 = __hip_atomic_load(&flags[(g * 4 + 2) * 16], __ATOMIC_RELAXED, __HIP_MEMORY_SCOPE_AGENT);
                uint32_t f3 = __hip_atomic_load(&flags[(g * 4 + 3) * 16], __ATOMIC_RELAXED, __HIP_MEMORY_SCOPE_AGENT);
                if (f0 >= tgt && f1 >= tgt && f2 >= tgt && f3 >= tgt) break;
                if (++spin > 100000000) break;   // safety: fail, don't hang
                __builtin_amdgcn_s_sleep(1);
            }
        }

        // ---- phase 6: stage h(t+1) into LDS A-frags ----
        {
            const unsigned long long* hgr =
                (const unsigned long long*)(hg32 + ((size_t)(g * 2 + buf) * 16 + m_s) * 128);
            #pragma unroll
            for (int i = 0; i < 4; ++i) {
                unsigned long long hv = __hip_atomic_load(
                    &hgr[(d0 >> 2) + i], __ATOMIC_RELAXED, __HIP_MEMORY_SCOPE_AGENT);
                int k0 = d0 + 4 * i;                   // A1 k-map (spot 3/3)
                int kk = k0 >> 5, off = k0 & 31;
                int q = (off & 15) >> 2, hi = off >> 4;
                int slot = (m_s + 16 * q) ^ ((2 * kk) & 63);
                *(uint64_t*)((uint8_t*)hx + kk * 1024 + slot * 16 + hi * 8) = hv;
            }
        }
        asm volatile("s_waitcnt lgkmcnt(0)\n\ts_barrier" ::: "memory");  // B3
    }

    // ---- output: each (m,j) owned by exactly one lane ----
    #pragma unroll
    for (int tl = 0; tl < 4; ++tl) {
        int gb = 16 * g + m_ew;
        out[gb * LSTM_H + jj[tl]]                      = hst[tl];
        out[LSTM_B * LSTM_H + gb * LSTM_H + jj[tl]]    = cst[tl];
    }
}

extern "C" void kernel_launch(void* const* d_in, const int* in_sizes, int n_in,
                              void* d_out, int out_size, void* d_ws, size_t ws_size,
                              hipStream_t stream) {
    const float* xs   = (const float*)d_in[0];  // [64,4096,256]
    const float* W_ih = (const float*)d_in[1];  // [1024,256]
    const float* W_hh = (const float*)d_in[2];  // [1024,256]
    const float* b    = (const float*)d_in[3];  // [1024]
    float* out = (float*)d_out;
    uint8_t* ws = (uint8_t*)d_ws;

    prep_frags<<<256, 256, 0, stream>>>(W_ih, W_hh, ws);
    lstm_r9<<<16, 256, 0, stream>>>(xs, b, ws, out);
}

// Round 7
// 13045.630 us; speedup vs baseline: 1.4657x; 1.4657x over previous
//
#include <hip/hip_runtime.h>
#include <hip/hip_fp16.h>
#include <stdint.h>

// LSTM_29042568856007: B=64, T=4096, D=256, H=256.
// Round 11: R9's MFMA core (verified) + restructured h-exchange. R10's
// handshake/sc0 experiment died without counters (likely protocol hang x
// huge spin bounds); all unproven mechanisms removed. This round uses ONLY
// R9-proven primitives (__hip_atomic_* agent scope):
//   - TAG-EMBEDDED DATA: each published u64 = (t+1)<<32 | h-pair. 8B aligned
//     store = single transaction -> no flag store, no vmcnt drain, no
//     publish barrier, no separate flag-poll RT. Consumer: 8 PARALLEL u64
//     loads, retry until all tags >= t+1 (~1 RT; R9 polled 4 flags with
//     SERIAL dependent loads = ~4x1500cy, the real step cost).
//   - placement bet: grid 32 = 8 groups x 4 parts, part p of group g at
//     blockIdx = g + 8p; under %8 round-robin dispatch the group shares one
//     XCD/L2. Placement-agnostic correctness (agent scope), speed-only bet.
//   - spin bound 2000 w/ proceed-on-timeout (fail visibly, never hang);
//     prep re-zeroes hg each launch so graph replays can't see stale tags.
//   - hg double-buffered by step parity; overwrite-before-read impossible
//     (publishing h(t+3) requires all parts consumed h(t+1)).
// Weights: R9-verified frag layout, 64 B-frags = 256 regs/lane, asm-pinned,
// zero per-step weight movement. MFMA 16x16x32_f16, M=8 batch rows/group.

#define LSTM_B 64
#define LSTM_T 4096
#define LSTM_D 256
#define LSTM_H 256

#define WS_HG_OFF (1u << 20)
// hg: uint64 [8 g][2 buf][8 m][128 jp]; entry = tag<<32 | f16 h-pair. 128 KB.

typedef __attribute__((ext_vector_type(8))) _Float16 half8;
typedef __attribute__((ext_vector_type(4))) float f32x4;

#define AST64(p, v) __hip_atomic_store((p), (v), __ATOMIC_RELAXED, __HIP_MEMORY_SCOPE_AGENT)
#define ALD64(p)    __hip_atomic_load((p), __ATOMIC_RELAXED, __HIP_MEMORY_SCOPE_AGENT)
#define BARLG()     asm volatile("s_waitcnt lgkmcnt(0)\n\ts_barrier" ::: "memory")

static __device__ __forceinline__ float sigmoidf_(float x) {
    return 1.0f / (1.0f + __expf(-x));
}
static __device__ __forceinline__ float tanhf_(float x) {
    float ax = fabsf(x);
    float e  = __expf(-2.0f * ax);
    float t  = (1.0f - e) / (1.0f + e);
    return copysignf(t, x);
}

// ws frags: uint4 frag[T=64][kk=16][lane=64]; identical to R9 (verified).
// slot n = T*16 + (lane&15); source gate row r = (n&3)*256 + (n>>2);
// k = 32*kk + 4*(lane>>4) + (j&3) + 16*(j>>2); k<256 -> W_hh else W_ih.
__global__ __launch_bounds__(256) void prep_frags(
    const float* __restrict__ W_ih, const float* __restrict__ W_hh,
    uint8_t* __restrict__ ws)
{
    int idx = blockIdx.x * blockDim.x + threadIdx.x;   // [0, 65536)
    uint4* Wp = (uint4*)ws;
    int lane = idx & 63;
    int kk   = (idx >> 6) & 15;
    int T    = idx >> 10;
    int n  = T * 16 + (lane & 15);
    int r  = ((n & 3) << 8) + (n >> 2);
    int kb = 32 * kk + 4 * (lane >> 4);
    uint32_t u[4];
    #pragma unroll
    for (int h = 0; h < 4; ++h) {
        uint32_t lohi[2];
        #pragma unroll
        for (int e = 0; e < 2; ++e) {
            int j = 2 * h + e;
            int k = kb + (j & 3) + 16 * (j >> 2);
            float v = (k < 256) ? W_hh[r * 256 + k] : W_ih[r * 256 + (k - 256)];
            lohi[e] = (uint32_t)__half_as_ushort(__float2half(v));
        }
        u[h] = lohi[0] | (lohi[1] << 16);
    }
    Wp[idx] = make_uint4(u[0], u[1], u[2], u[3]);
    // re-zero hg each launch (graph replay: stale tags must not survive)
    if (idx < 32768) ((uint32_t*)(ws + WS_HG_OFF))[idx] = 0u;
}

__global__ __launch_bounds__(256, 1) void lstm_r11(
    const float* __restrict__ xs,      // [B, T, D] fp32
    const float* __restrict__ bias_g,  // [4H]
    uint8_t* __restrict__ ws,
    float* __restrict__ out)           // h[B,H] then c[B,H]
{
    const int tid = threadIdx.x;
    const int l   = tid & 63;
    const int w   = tid >> 6;            // wave [0,4)
    const int g   = blockIdx.x & 7;      // group: batches 8g..8g+7 (XCD target)
    const int p   = blockIdx.x >> 3;     // slot-part: slots 256p..256p+255

    const uint4* WF = (const uint4*)ws;
    uint64_t* hg64  = (uint64_t*)(ws + WS_HG_OFF);

    __shared__ uint4 hx[16 * 64];        // A-frags [kk][laneSlot], 16 KiB

    // ---- one-time: this WG's 64 B-frags into registers (R9-verified) ----
    uint4 wf[4][16];
    #pragma unroll
    for (int tl = 0; tl < 4; ++tl) {
        int T = p * 16 + w * 4 + tl;
        #pragma unroll
        for (int kk = 0; kk < 16; ++kk)
            wf[tl][kk] = WF[(T * 16 + kk) * 64 + l];
    }
    #pragma unroll
    for (int tl = 0; tl < 4; ++tl)
        #pragma unroll
        for (int kk = 0; kk < 16; ++kk)
            asm volatile("" : "+v"(wf[tl][kk].x), "+v"(wf[tl][kk].y),
                              "+v"(wf[tl][kk].z), "+v"(wf[tl][kk].w));

    // ---- per-lane ew constants (R9-verified; D: col=l&15, row=4*(l>>4)+reg) ----
    const int  c2   = l & 3;
    const int  qa   = l >> 4;
    const bool c2b0 = (c2 & 1) != 0, c2b1 = (c2 & 2) != 0;
    const int  m_ew = 4 * qa + c2;       // batch row this lane finalizes
    float bias[4];
    int   jj[4];
    #pragma unroll
    for (int tl = 0; tl < 4; ++tl) {
        int T    = p * 16 + w * 4 + tl;
        int slot = T * 16 + (l & 15);
        int r    = ((slot & 3) << 8) + (slot >> 2);
        bias[tl] = bias_g[r];
        jj[tl]   = slot >> 2;            // global h-col [0,256)
    }

    // ---- staging ids: thread covers (m_s, cols d0..d0+15) ----
    const int m_s = tid >> 4;            // [0,16); only <8 are real batches
    const int d0  = (tid & 15) * 16;
    const float* xrow = xs + (size_t)(8 * g + (m_s & 7)) * LSTM_T * LSTM_D + d0;

    // ---- prologue: zero hx; stage x(0); prefetch x(1),x(2) ----
    hx[tid]       = make_uint4(0, 0, 0, 0);
    hx[tid + 256] = make_uint4(0, 0, 0, 0);
    hx[tid + 512] = make_uint4(0, 0, 0, 0);
    hx[tid + 768] = make_uint4(0, 0, 0, 0);
    float4 xb[2][4];
    if (m_s < 8) {
        #pragma unroll
        for (int i = 0; i < 4; ++i) {
            float4 xv = ((const float4*)xrow)[i];
            __half2 h0 = __floats2half2_rn(xv.x, xv.y);
            __half2 h1 = __floats2half2_rn(xv.z, xv.w);
            uint64_t v = (uint64_t)__builtin_bit_cast(uint32_t, h0)
                       | ((uint64_t)__builtin_bit_cast(uint32_t, h1) << 32);
            int k0 = 256 + d0 + 4 * i;
            int kk = k0 >> 5, off = k0 & 31;
            int q = (off & 15) >> 2, hi = off >> 4;
            int slot = (m_s + 16 * q) ^ ((2 * kk) & 63);
            *(uint64_t*)((uint8_t*)hx + kk * 1024 + slot * 16 + hi * 8) = v;
        }
        #pragma unroll
        for (int i = 0; i < 4; ++i) xb[0][i] = ((const float4*)(xrow + (size_t)1 * LSTM_D))[i];
        #pragma unroll
        for (int i = 0; i < 4; ++i) xb[1][i] = ((const float4*)(xrow + (size_t)2 * LSTM_D))[i];
    }
    BARLG();

    float cst[4] = {0, 0, 0, 0}, hst[4] = {0, 0, 0, 0};

#define STEP(T_, PAR) do {                                                          \
    /* phase 1: A-frags [h_t | x_t] into regs */                                    \
    uint4 af[16];                                                                   \
    _Pragma("unroll")                                                               \
    for (int kk = 0; kk < 16; ++kk)                                                 \
        af[kk] = hx[kk * 64 + (l ^ ((2 * kk) & 63))];                               \
    BARLG();                                                                        \
    /* phase 2: stage x(T_+1); prefetch x(T_+3) into xb[PAR] */                     \
    if (m_s < 8) {                                                                  \
        _Pragma("unroll")                                                           \
        for (int i = 0; i < 4; ++i) {                                               \
            float4 xv = xb[PAR][i];                                                 \
            __half2 h0 = __floats2half2_rn(xv.x, xv.y);                             \
            __half2 h1 = __floats2half2_rn(xv.z, xv.w);                             \
            uint64_t v = (uint64_t)__builtin_bit_cast(uint32_t, h0)                 \
                       | ((uint64_t)__builtin_bit_cast(uint32_t, h1) << 32);        \
            int k0 = 256 + d0 + 4 * i;                                              \
            int kk = k0 >> 5, off = k0 & 31;                                        \
            int q = (off & 15) >> 2, hi = off >> 4;                                 \
            int slot = (m_s + 16 * q) ^ ((2 * kk) & 63);                            \
            *(uint64_t*)((uint8_t*)hx + kk * 1024 + slot * 16 + hi * 8) = v;        \
        }                                                                           \
        int tn = (T_ + 3 < LSTM_T) ? T_ + 3 : T_;                                   \
        const float4* nx = (const float4*)(xrow + (size_t)tn * LSTM_D);             \
        _Pragma("unroll")                                                           \
        for (int i = 0; i < 4; ++i) xb[PAR][i] = nx[i];                             \
    }                                                                               \
    /* phase 3: MFMA, 4 tiles x 16 kk */                                            \
    f32x4 acc[4];                                                                   \
    _Pragma("unroll")                                                               \
    for (int tl = 0; tl < 4; ++tl)                                                  \
        acc[tl] = (f32x4){bias[tl], bias[tl], bias[tl], bias[tl]};                  \
    _Pragma("unroll")                                                               \
    for (int kk = 0; kk < 16; ++kk) {                                               \
        half8 a = __builtin_bit_cast(half8, af[kk]);                                \
        _Pragma("unroll")                                                           \
        for (int tl = 0; tl < 4; ++tl)                                              \
            acc[tl] = __builtin_amdgcn_mfma_f32_16x16x32_f16(                       \
                a, __builtin_bit_cast(half8, wf[tl][kk]), acc[tl], 0, 0, 0);        \
    }                                                                               \
    /* phase 4: gate gather + lstm ew + pack (R9-verified) */                       \
    uint32_t hpair[4];                                                              \
    _Pragma("unroll")                                                               \
    for (int tl = 0; tl < 4; ++tl) {                                                \
        f32x4 a = acc[tl];                                                          \
        float s01  = c2b0 ? a.y : a.x;                                              \
        float s23  = c2b0 ? a.w : a.z;                                              \
        float s01b = c2b0 ? a.x : a.y;                                              \
        float s23b = c2b0 ? a.z : a.w;                                              \
        float own = c2b1 ? s23  : s01;                                              \
        float v1  = c2b1 ? s23b : s01b;                                             \
        float v2  = c2b1 ? s01  : s23;                                              \
        float v3  = c2b1 ? s01b : s23b;                                             \
        float r1 = __shfl_xor(v1, 1, 64);                                           \
        float r2 = __shfl_xor(v2, 2, 64);                                           \
        float r3 = __shfl_xor(v3, 3, 64);                                           \
        float gi = c2b1 ? (c2b0 ? r3 : r2) : (c2b0 ? r1 : own);                     \
        float gf = c2b1 ? (c2b0 ? r2 : r3) : (c2b0 ? own : r1);                     \
        float gg = c2b1 ? (c2b0 ? r1 : own) : (c2b0 ? r3 : r2);                     \
        float go = c2b1 ? (c2b0 ? own : r1) : (c2b0 ? r2 : r3);                     \
        float cc = cst[tl];                                                         \
        cc = sigmoidf_(gf) * cc + sigmoidf_(gi) * tanhf_(gg);                       \
        float hh = sigmoidf_(go) * tanhf_(cc);                                      \
        cst[tl] = cc; hst[tl] = hh;                                                 \
        uint32_t u  = (uint32_t)__half_as_ushort(__float2half(hh));                 \
        uint32_t up = (uint32_t)__shfl_xor((int)u, 4, 64);                          \
        hpair[tl] = (u & 0xffffu) | (up << 16);                                     \
    }                                                                               \
    /* phase 5: publish h(T_+1) as self-tagged u64s -- no flag, no drain */         \
    {                                                                               \
        const int buf = (PAR) ^ 1;                                                  \
        if (l < 32 && (l & 4) == 0) {                                               \
            uint64_t* hgrow = hg64 + (((size_t)g * 2 + buf) * 8 + m_ew) * 128;      \
            const uint64_t tagw = ((uint64_t)(uint32_t)(T_ + 1)) << 32;             \
            _Pragma("unroll")                                                       \
            for (int tl = 0; tl < 4; ++tl)                                          \
                AST64(&hgrow[jj[tl] >> 1], tagw | (uint64_t)hpair[tl]);             \
        }                                                                           \
        /* phase 6: poll 8 parallel u64s until tags fresh; stage h(T_+1) */         \
        if (m_s < 8) {                                                              \
            const uint32_t tgt = (uint32_t)(T_ + 1);                                \
            uint64_t* hgr = hg64 + (((size_t)g * 2 + buf) * 8 + m_s) * 128          \
                          + (d0 >> 1);                                              \
            uint64_t hv[8];                                                         \
            _Pragma("unroll")                                                       \
            for (int i = 0; i < 8; ++i) hv[i] = ALD64(&hgr[i]);                     \
            int spin = 0;                                                           \
            while (true) {                                                          \
                bool ok = true;                                                     \
                _Pragma("unroll")                                                   \
                for (int i = 0; i < 8; ++i) ok &= ((uint32_t)(hv[i] >> 32) >= tgt); \
                if (ok || ++spin > 2000) break;                                     \
                _Pragma("unroll")                                                   \
                for (int i = 0; i < 8; ++i) hv[i] = ALD64(&hgr[i]);                 \
            }                                                                       \
            _Pragma("unroll")                                                       \
            for (int i = 0; i < 8; ++i) {                                           \
                uint32_t pr = (uint32_t)hv[i];                                      \
                int k0 = d0 + 2 * i;                                                \
                int kk = k0 >> 5, off = k0 & 31;                                    \
                int q = (off & 15) >> 2, hi = off >> 4;                             \
                int slot = (m_s + 16 * q) ^ ((2 * kk) & 63);                        \
                *(uint32_t*)((uint8_t*)hx + kk * 1024 + slot * 16 + hi * 8          \
                             + ((off & 3) << 1)) = pr;                              \
            }                                                                       \
        }                                                                           \
        BARLG();                                                                    \
    }                                                                               \
} while (0)

    for (int t = 0; t < LSTM_T; t += 2) {
        STEP(t, 0);
        STEP(t + 1, 1);
    }
#undef STEP

    if (m_ew < 8) {
        #pragma unroll
        for (int tl = 0; tl < 4; ++tl) {
            int gb = 8 * g + m_ew;
            out[gb * LSTM_H + jj[tl]]                   = hst[tl];
            out[LSTM_B * LSTM_H + gb * LSTM_H + jj[tl]] = cst[tl];
        }
    }
}

extern "C" void kernel_launch(void* const* d_in, const int* in_sizes, int n_in,
                              void* d_out, int out_size, void* d_ws, size_t ws_size,
                              hipStream_t stream) {
    const float* xs   = (const float*)d_in[0];  // [64,4096,256]
    const float* W_ih = (const float*)d_in[1];  // [1024,256]
    const float* W_hh = (const float*)d_in[2];  // [1024,256]
    const float* b    = (const float*)d_in[3];  // [1024]
    float* out = (float*)d_out;
    uint8_t* ws = (uint8_t*)d_ws;

    prep_frags<<<256, 256, 0, stream>>>(W_ih, W_hh, ws);
    lstm_r11<<<32, 256, 0, stream>>>(xs, b, ws, out);
}

// Round 9
// 12353.309 us; speedup vs baseline: 1.5479x; 1.0560x over previous
//
#include <hip/hip_runtime.h>
#include <hip/hip_fp16.h>
#include <stdint.h>

// LSTM_29042568856007: B=64, T=4096, D=256, H=256.
// Round 13: R11 transport (agent atomics via MALL -- R12's L2-local sc0 path
// FAILED correctness and is abandoned per pre-commit) + critical-path split.
// R11 step = 7.5k cyc = ~1.5-2k compute + ~6k retry-aligned MALL wait, with
// the x-half of the MFMA work needlessly serialized inside the poll->publish
// window. This round:
//   phase A (critical):  ds_read 8 h-frags -> 32 h-MFMAs into PRE-SEEDED acc
//                        -> ew -> publish tagged u64s          (~900 cyc)
//   phase B (wait-fill): stage x(t+1), prefetch x(t+3), seed next acc =
//                        bias + 32 x-MFMAs (kk 8..15)          (hidden)
//   phase C:             poll h(t+1) (R11 verbatim), stage, barrier
// Double accumulators (accA/accB) alternate across the existing 2-step
// unroll. Buffer safety identical to R11: publish h(T+3) into buf requires
// passing step T+1's poll (all parts published h(T+2)), which requires every
// part passed step T's phase C (consumed h(T+1) from that buf).
// Weights: R9-verified frag layout, 64 B-frags = 256 regs asm-pinned.

#define LSTM_B 64
#define LSTM_T 4096
#define LSTM_D 256
#define LSTM_H 256

#define WS_HG_OFF (1u << 20)
// hg: uint64 [8 g][2 buf][8 m][128 jp]; entry = tag<<32 | f16 h-pair. 128 KB.

typedef __attribute__((ext_vector_type(8))) _Float16 half8;
typedef __attribute__((ext_vector_type(4))) float f32x4;

#define AST64(p, v) __hip_atomic_store((p), (v), __ATOMIC_RELAXED, __HIP_MEMORY_SCOPE_AGENT)
#define ALD64(p)    __hip_atomic_load((p), __ATOMIC_RELAXED, __HIP_MEMORY_SCOPE_AGENT)
#define BARLG()     asm volatile("s_waitcnt lgkmcnt(0)\n\ts_barrier" ::: "memory")

static __device__ __forceinline__ float sigmoidf_(float x) {
    return 1.0f / (1.0f + __expf(-x));
}
static __device__ __forceinline__ float tanhf_(float x) {
    float ax = fabsf(x);
    float e  = __expf(-2.0f * ax);
    float t  = (1.0f - e) / (1.0f + e);
    return copysignf(t, x);
}

// ws frags: uint4 frag[T=64][kk=16][lane=64]; identical to R9/R11 (verified).
// slot n = T*16 + (lane&15); source gate row r = (n&3)*256 + (n>>2);
// k = 32*kk + 4*(lane>>4) + (j&3) + 16*(j>>2); k<256 -> W_hh else W_ih.
__global__ __launch_bounds__(256) void prep_frags(
    const float* __restrict__ W_ih, const float* __restrict__ W_hh,
    uint8_t* __restrict__ ws)
{
    int idx = blockIdx.x * blockDim.x + threadIdx.x;   // [0, 65536)
    uint4* Wp = (uint4*)ws;
    int lane = idx & 63;
    int kk   = (idx >> 6) & 15;
    int T    = idx >> 10;
    int n  = T * 16 + (lane & 15);
    int r  = ((n & 3) << 8) + (n >> 2);
    int kb = 32 * kk + 4 * (lane >> 4);
    uint32_t u[4];
    #pragma unroll
    for (int h = 0; h < 4; ++h) {
        uint32_t lohi[2];
        #pragma unroll
        for (int e = 0; e < 2; ++e) {
            int j = 2 * h + e;
            int k = kb + (j & 3) + 16 * (j >> 2);
            float v = (k < 256) ? W_hh[r * 256 + k] : W_ih[r * 256 + (k - 256)];
            lohi[e] = (uint32_t)__half_as_ushort(__float2half(v));
        }
        u[h] = lohi[0] | (lohi[1] << 16);
    }
    Wp[idx] = make_uint4(u[0], u[1], u[2], u[3]);
    // re-zero hg each launch (graph replay: stale tags must not survive)
    if (idx < 32768) ((uint32_t*)(ws + WS_HG_OFF))[idx] = 0u;
}

__global__ __launch_bounds__(256, 1) void lstm_r13(
    const float* __restrict__ xs,      // [B, T, D] fp32
    const float* __restrict__ bias_g,  // [4H]
    uint8_t* __restrict__ ws,
    float* __restrict__ out)           // h[B,H] then c[B,H]
{
    const int tid = threadIdx.x;
    const int l   = tid & 63;
    const int w   = tid >> 6;            // wave [0,4)
    const int g   = blockIdx.x & 7;      // group: batches 8g..8g+7
    const int p   = blockIdx.x >> 3;     // slot-part: slots 256p..256p+255

    const uint4* WF = (const uint4*)ws;
    uint64_t* hg64  = (uint64_t*)(ws + WS_HG_OFF);

    __shared__ uint4 hx[16 * 64];        // A-frags [kk][laneSlot]; kk<8 = h, kk>=8 = x

    // ---- one-time: this WG's 64 B-frags into registers (R9-verified) ----
    uint4 wf[4][16];
    #pragma unroll
    for (int tl = 0; tl < 4; ++tl) {
        int T = p * 16 + w * 4 + tl;
        #pragma unroll
        for (int kk = 0; kk < 16; ++kk)
            wf[tl][kk] = WF[(T * 16 + kk) * 64 + l];
    }
    #pragma unroll
    for (int tl = 0; tl < 4; ++tl)
        #pragma unroll
        for (int kk = 0; kk < 16; ++kk)
            asm volatile("" : "+v"(wf[tl][kk].x), "+v"(wf[tl][kk].y),
                              "+v"(wf[tl][kk].z), "+v"(wf[tl][kk].w));

    // ---- per-lane ew constants (R9-verified; D: col=l&15, row=4*(l>>4)+reg) ----
    const int  c2   = l & 3;
    const int  qa   = l >> 4;
    const bool c2b0 = (c2 & 1) != 0, c2b1 = (c2 & 2) != 0;
    const int  m_ew = 4 * qa + c2;       // batch row this lane finalizes
    float bias[4];
    int   jj[4];
    #pragma unroll
    for (int tl = 0; tl < 4; ++tl) {
        int T    = p * 16 + w * 4 + tl;
        int slot = T * 16 + (l & 15);
        int r    = ((slot & 3) << 8) + (slot >> 2);
        bias[tl] = bias_g[r];
        jj[tl]   = slot >> 2;            // global h-col [0,256)
    }

    // ---- staging ids: thread covers (m_s, cols d0..d0+15) ----
    const int m_s = tid >> 4;            // [0,16); only <8 are real batches
    const int d0  = (tid & 15) * 16;
    const float* xrow = xs + (size_t)(8 * g + (m_s & 7)) * LSTM_T * LSTM_D + d0;

    // ---- prologue: zero hx; stage x(0); prefetch x(1),x(2) ----
    hx[tid]       = make_uint4(0, 0, 0, 0);
    hx[tid + 256] = make_uint4(0, 0, 0, 0);
    hx[tid + 512] = make_uint4(0, 0, 0, 0);
    hx[tid + 768] = make_uint4(0, 0, 0, 0);
    float4 xb[2][4];
    if (m_s < 8) {
        #pragma unroll
        for (int i = 0; i < 4; ++i) {
            float4 xv = ((const float4*)xrow)[i];
            __half2 h0 = __floats2half2_rn(xv.x, xv.y);
            __half2 h1 = __floats2half2_rn(xv.z, xv.w);
            uint64_t v = (uint64_t)__builtin_bit_cast(uint32_t, h0)
                       | ((uint64_t)__builtin_bit_cast(uint32_t, h1) << 32);
            int k0 = 256 + d0 + 4 * i;
            int kk = k0 >> 5, off = k0 & 31;
            int q = (off & 15) >> 2, hi = off >> 4;
            int slot = (m_s + 16 * q) ^ ((2 * kk) & 63);
            *(uint64_t*)((uint8_t*)hx + kk * 1024 + slot * 16 + hi * 8) = v;
        }
        #pragma unroll
        for (int i = 0; i < 4; ++i) xb[0][i] = ((const float4*)(xrow + (size_t)1 * LSTM_D))[i];
        #pragma unroll
        for (int i = 0; i < 4; ++i) xb[1][i] = ((const float4*)(xrow + (size_t)2 * LSTM_D))[i];
    }
    BARLG();                             // x(0) staged

    // ---- seed accA = bias + x(0)-half (kk 8..15) ----
    f32x4 accA[4], accB[4];
    {
        uint4 afx[8];
        #pragma unroll
        for (int kx = 0; kx < 8; ++kx) {
            int kk = kx + 8;
            afx[kx] = hx[kk * 64 + (l ^ ((2 * kk) & 63))];
        }
        #pragma unroll
        for (int tl = 0; tl < 4; ++tl)
            accA[tl] = (f32x4){bias[tl], bias[tl], bias[tl], bias[tl]};
        #pragma unroll
        for (int kx = 0; kx < 8; ++kx) {
            half8 a = __builtin_bit_cast(half8, afx[kx]);
            #pragma unroll
            for (int tl = 0; tl < 4; ++tl)
                accA[tl] = __builtin_amdgcn_mfma_f32_16x16x32_f16(
                    a, __builtin_bit_cast(half8, wf[tl][kx + 8]), accA[tl], 0, 0, 0);
        }
    }

    float cst[4] = {0, 0, 0, 0}, hst[4] = {0, 0, 0, 0};

#define STEP(T_, PAR, ACC_C, ACC_N) do {                                            \
    /* ---- phase A (critical): h-half MFMA -> ew -> publish ---- */                \
    uint4 afh[8];                                                                   \
    _Pragma("unroll")                                                               \
    for (int kk = 0; kk < 8; ++kk)                                                  \
        afh[kk] = hx[kk * 64 + (l ^ ((2 * kk) & 63))];                              \
    _Pragma("unroll")                                                               \
    for (int kk = 0; kk < 8; ++kk) {                                                \
        half8 a = __builtin_bit_cast(half8, afh[kk]);                               \
        _Pragma("unroll")                                                           \
        for (int tl = 0; tl < 4; ++tl)                                              \
            ACC_C[tl] = __builtin_amdgcn_mfma_f32_16x16x32_f16(                     \
                a, __builtin_bit_cast(half8, wf[tl][kk]), ACC_C[tl], 0, 0, 0);      \
    }                                                                               \
    uint32_t hpair[4];                                                              \
    _Pragma("unroll")                                                               \
    for (int tl = 0; tl < 4; ++tl) {                                                \
        f32x4 a = ACC_C[tl];                                                        \
        float s01  = c2b0 ? a.y : a.x;                                              \
        float s23  = c2b0 ? a.w : a.z;                                              \
        float s01b = c2b0 ? a.x : a.y;                                              \
        float s23b = c2b0 ? a.z : a.w;                                              \
        float own = c2b1 ? s23  : s01;                                              \
        float v1  = c2b1 ? s23b : s01b;                                             \
        float v2  = c2b1 ? s01  : s23;                                              \
        float v3  = c2b1 ? s01b : s23b;                                             \
        float r1 = __shfl_xor(v1, 1, 64);                                           \
        float r2 = __shfl_xor(v2, 2, 64);                                           \
        float r3 = __shfl_xor(v3, 3, 64);                                           \
        float gi = c2b1 ? (c2b0 ? r3 : r2) : (c2b0 ? r1 : own);                     \
        float gf = c2b1 ? (c2b0 ? r2 : r3) : (c2b0 ? own : r1);                     \
        float gg = c2b1 ? (c2b0 ? r1 : own) : (c2b0 ? r3 : r2);                     \
        float go = c2b1 ? (c2b0 ? own : r1) : (c2b0 ? r2 : r3);                     \
        float cc = cst[tl];                                                         \
        cc = sigmoidf_(gf) * cc + sigmoidf_(gi) * tanhf_(gg);                       \
        float hh = sigmoidf_(go) * tanhf_(cc);                                      \
        cst[tl] = cc; hst[tl] = hh;                                                 \
        uint32_t u  = (uint32_t)__half_as_ushort(__float2half(hh));                 \
        uint32_t up = (uint32_t)__shfl_xor((int)u, 4, 64);                          \
        hpair[tl] = (u & 0xffffu) | (up << 16);                                     \
    }                                                                               \
    {                                                                               \
        const int buf = (PAR) ^ 1;                                                  \
        if (l < 32 && (l & 4) == 0) {                                               \
            uint64_t* hgrow = hg64 + (((size_t)g * 2 + buf) * 8 + m_ew) * 128;      \
            const uint64_t tagw = ((uint64_t)(uint32_t)(T_ + 1)) << 32;             \
            _Pragma("unroll")                                                       \
            for (int tl = 0; tl < 4; ++tl)                                          \
                AST64(&hgrow[jj[tl] >> 1], tagw | (uint64_t)hpair[tl]);             \
        }                                                                           \
        /* ---- phase B: stage x(T_+1); prefetch x(T_+3) ---- */                    \
        if (m_s < 8) {                                                              \
            _Pragma("unroll")                                                       \
            for (int i = 0; i < 4; ++i) {                                           \
                float4 xv = xb[PAR][i];                                             \
                __half2 h0 = __floats2half2_rn(xv.x, xv.y);                         \
                __half2 h1 = __floats2half2_rn(xv.z, xv.w);                         \
                uint64_t v = (uint64_t)__builtin_bit_cast(uint32_t, h0)             \
                           | ((uint64_t)__builtin_bit_cast(uint32_t, h1) << 32);    \
                int k0 = 256 + d0 + 4 * i;                                          \
                int kk = k0 >> 5, off = k0 & 31;                                    \
                int q = (off & 15) >> 2, hi = off >> 4;                             \
                int slot = (m_s + 16 * q) ^ ((2 * kk) & 63);                        \
                *(uint64_t*)((uint8_t*)hx + kk * 1024 + slot * 16 + hi * 8) = v;    \
            }                                                                       \
            int tn = (T_ + 3 < LSTM_T) ? T_ + 3 : T_;                               \
            const float4* nx = (const float4*)(xrow + (size_t)tn * LSTM_D);         \
            _Pragma("unroll")                                                       \
            for (int i = 0; i < 4; ++i) xb[PAR][i] = nx[i];                         \
        }                                                                           \
        BARLG();   /* barrier1: x(T_+1) staged; all phase-A LDS reads done */       \
        /* issue x-frag reads (independent of poll) */                              \
        uint4 afx[8];                                                               \
        _Pragma("unroll")                                                           \
        for (int kx = 0; kx < 8; ++kx) {                                            \
            int kk = kx + 8;                                                        \
            afx[kx] = hx[kk * 64 + (l ^ ((2 * kk) & 63))];                          \
        }                                                                           \
        /* ---- phase C: poll h(T_+1) (R11 verbatim), stage into kk 0..7 ---- */    \
        if (m_s < 8) {                                                              \
            const uint32_t tgt = (uint32_t)(T_ + 1);                                \
            uint64_t* hgr = hg64 + (((size_t)g * 2 + buf) * 8 + m_s) * 128          \
                          + (d0 >> 1);                                              \
            uint64_t hv[8];                                                         \
            _Pragma("unroll")                                                       \
            for (int i = 0; i < 8; ++i) hv[i] = ALD64(&hgr[i]);                     \
            int spin = 0;                                                           \
            while (true) {                                                          \
                bool ok = true;                                                     \
                _Pragma("unroll")                                                   \
                for (int i = 0; i < 8; ++i) ok &= ((uint32_t)(hv[i] >> 32) >= tgt); \
                if (ok || ++spin > 2000) break;                                     \
                _Pragma("unroll")                                                   \
                for (int i = 0; i < 8; ++i) hv[i] = ALD64(&hgr[i]);                 \
            }                                                                       \
            _Pragma("unroll")                                                       \
            for (int i = 0; i < 8; ++i) {                                           \
                uint32_t pr = (uint32_t)hv[i];                                      \
                int k0 = d0 + 2 * i;                                                \
                int kk = k0 >> 5, off = k0 & 31;                                    \
                int q = (off & 15) >> 2, hi = off >> 4;                             \
                int slot = (m_s + 16 * q) ^ ((2 * kk) & 63);                        \
                *(uint32_t*)((uint8_t*)hx + kk * 1024 + slot * 16 + hi * 8          \
                             + ((off & 3) << 1)) = pr;                              \
            }                                                                       \
        }                                                                           \
        /* seed next acc = bias + x(T_+1)-half while the stage drains */            \
        _Pragma("unroll")                                                           \
        for (int tl = 0; tl < 4; ++tl)                                              \
            ACC_N[tl] = (f32x4){bias[tl], bias[tl], bias[tl], bias[tl]};            \
        _Pragma("unroll")                                                           \
        for (int kx = 0; kx < 8; ++kx) {                                            \
            half8 a = __builtin_bit_cast(half8, afx[kx]);                           \
            _Pragma("unroll")                                                       \
            for (int tl = 0; tl < 4; ++tl)                                          \
                ACC_N[tl] = __builtin_amdgcn_mfma_f32_16x16x32_f16(                 \
                    a, __builtin_bit_cast(half8, wf[tl][kx + 8]), ACC_N[tl],        \
                    0, 0, 0);                                                       \
        }                                                                           \
        BARLG();   /* barrier2: h(T_+1) frags visible for next phase A */           \
    }                                                                               \
} while (0)

    for (int t = 0; t < LSTM_T; t += 2) {
        STEP(t,     0, accA, accB);
        STEP(t + 1, 1, accB, accA);
    }
#undef STEP

    if (m_ew < 8) {
        #pragma unroll
        for (int tl = 0; tl < 4; ++tl) {
            int gb = 8 * g + m_ew;
            out[gb * LSTM_H + jj[tl]]                   = hst[tl];
            out[LSTM_B * LSTM_H + gb * LSTM_H + jj[tl]] = cst[tl];
        }
    }
}

extern "C" void kernel_launch(void* const* d_in, const int* in_sizes, int n_in,
                              void* d_out, int out_size, void* d_ws, size_t ws_size,
                              hipStream_t stream) {
    const float* xs   = (const float*)d_in[0];  // [64,4096,256]
    const float* W_ih = (const float*)d_in[1];  // [1024,256]
    const float* W_hh = (const float*)d_in[2];  // [1024,256]
    const float* b    = (const float*)d_in[3];  // [1024]
    float* out = (float*)d_out;
    uint8_t* ws = (uint8_t*)d_ws;

    prep_frags<<<256, 256, 0, stream>>>(W_ih, W_hh, ws);
    lstm_r13<<<32, 256, 0, stream>>>(xs, b, ws, out);
}